// Round 16
// baseline (95.827 us; speedup 1.0000x reference)
//
#include <hip/hip_runtime.h>
#include <hip/hip_bf16.h>

#define FD 256      // feature dim
#define NTOT 768    // Q|K|V channels
#define TB 8        // tokens per block
#define NT 1024     // 16 waves (4/SIMD at 1 block/CU -- 2x R13's TLP)
#define ASTR 264    // bf16 row stride for A staging (256+8)
#define QSTR 772    // fp32 row stride for qkv tile (768+4)
#define NM 15       // Taylor moments

typedef __attribute__((ext_vector_type(8))) short bf16x8;
typedef __attribute__((ext_vector_type(4))) float f32x4;

__device__ __forceinline__ float fast_rcp(float x) {
#if __has_builtin(__builtin_amdgcn_rcpf)
    return __builtin_amdgcn_rcpf(x);
#else
    return 1.0f / x;
#endif
}

__device__ __forceinline__ unsigned bits(float a) {
    union { float f; unsigned u; } c; c.f = a; return c.u;
}
__device__ __forceinline__ float hi_f(float a) {       // bf16-truncated value
    union { unsigned u; float f; } c; c.u = bits(a) & 0xFFFF0000u; return c.f;
}
__device__ __forceinline__ unsigned pack_hi2(float a, float b) {
    return (bits(a) >> 16) | (bits(b) & 0xFFFF0000u);  // two bf16 from tops
}

union SmemU {
    struct { short Ah[16 * ASTR]; short Al[16 * ASTR]; } a;  // 16.9 KB (K-loop)
    float qkv[TB * QSTR];                                    // 24.7 KB (attn)
};

// ---------------------------------------------------------------------------
// ONE-dispatch fused kernel (launch overhead ~10us/dispatch dominates the
// controllable budget -- R13/R14/R15 A/B evidence). Block-local fusion at
// TB=8 -> grid 256 = minimum-possible W traffic (786 KB/CU L2 stream, the
// ~5.8us floor). 16 waves = 4/SIMD to hide it (R13 had only 2).
//   Phase 1: QKV tile (8 tok x 768 ch) = x @ W^T + b, split-bf16 MFMA
//     (C ~= AhBh+AhBl+AlBh, dropped AlBl ~2^-16 rel). A staged once in LDS;
//     W per-lane fp32 from global, split in-register (VALU hides under the
//     L2 stream); K-loop barrier-free. M=16 tile: A rows 8-15 garbage,
//     affect only discarded D rows 8-15.
//   Phase 2: Taylor softmax-attention on the LDS tile; 2 waves per token
//     (redundant moment build, halved Horner). f(c)=sum_n c^n M_n/n!,
//     M_n=sum_j k_j^n v_j; deg-14 remainder < 1e-6.
// ---------------------------------------------------------------------------
__global__ __launch_bounds__(NT, 1) void fused_ja(
    const float* __restrict__ x,
    const float* __restrict__ Wq, const float* __restrict__ bq,
    const float* __restrict__ Wk, const float* __restrict__ bk,
    const float* __restrict__ Wv, const float* __restrict__ bv,
    float* __restrict__ out)
{
    __shared__ SmemU sm;

    const int tid  = threadIdx.x;
    const int lane = tid & 63;
    const int wid  = tid >> 6;          // 0..15
    const int ln   = lane & 15;
    const int quad = lane >> 4;
    const int t0   = blockIdx.x * TB;

    // ---- stage x tile (8 tok x 256 k) -> Ah/Al; threads 0..511 ----
    if (tid < 512) {
        const int r = tid >> 6;                 // 0..7 token
        const int c = (tid & 63) * 4;           // 0..252
        const float4 v = *(const float4*)(x + (size_t)(t0 + r) * FD + c);
        uint2 ph, pl;
        ph.x = pack_hi2(v.x, v.y); ph.y = pack_hi2(v.z, v.w);
        pl.x = pack_hi2(v.x - hi_f(v.x), v.y - hi_f(v.y));
        pl.y = pack_hi2(v.z - hi_f(v.z), v.w - hi_f(v.w));
        *(uint2*)&sm.a.Ah[r * ASTR + c] = ph;
        *(uint2*)&sm.a.Al[r * ASTR + c] = pl;
    }
    __syncthreads();

    // ---- K-loop: wave owns 48 channels = 3 n-tiles, barrier-free ----
    const int chw = wid * 48;
    const float* wrow[3];
    #pragma unroll
    for (int t = 0; t < 3; ++t) {
        const int chb = chw + t * 16;           // 16-tile within one matrix
        const float* __restrict__ Wp = (chb < 256) ? Wq : (chb < 512) ? Wk : Wv;
        wrow[t] = Wp + (size_t)((chb & 255) + ln) * FD;
    }

    f32x4 acc[3];
    #pragma unroll
    for (int t = 0; t < 3; ++t) acc[t] = (f32x4){0.f, 0.f, 0.f, 0.f};

    #pragma unroll
    for (int s = 0; s < 8; ++s) {
        const bf16x8 ah = *(const bf16x8*)&sm.a.Ah[ln * ASTR + s * 32 + quad * 8];
        const bf16x8 al = *(const bf16x8*)&sm.a.Al[ln * ASTR + s * 32 + quad * 8];
        #pragma unroll
        for (int t = 0; t < 3; ++t) {
            const float4 v0 = *(const float4*)(wrow[t] + s * 32 + quad * 8);
            const float4 v1 = *(const float4*)(wrow[t] + s * 32 + quad * 8 + 4);
            uint2 ph, pl, qh, ql;
            ph.x = pack_hi2(v0.x, v0.y); ph.y = pack_hi2(v0.z, v0.w);
            pl.x = pack_hi2(v0.x - hi_f(v0.x), v0.y - hi_f(v0.y));
            pl.y = pack_hi2(v0.z - hi_f(v0.z), v0.w - hi_f(v0.w));
            qh.x = pack_hi2(v1.x, v1.y); qh.y = pack_hi2(v1.z, v1.w);
            ql.x = pack_hi2(v1.x - hi_f(v1.x), v1.y - hi_f(v1.y));
            ql.y = pack_hi2(v1.z - hi_f(v1.z), v1.w - hi_f(v1.w));
            union { uint2 u[2]; bf16x8 b; } bh, bl;
            bh.u[0] = ph; bh.u[1] = qh;
            bl.u[0] = pl; bl.u[1] = ql;
            acc[t] = __builtin_amdgcn_mfma_f32_16x16x32_bf16(ah, bh.b, acc[t], 0, 0, 0);
            acc[t] = __builtin_amdgcn_mfma_f32_16x16x32_bf16(ah, bl.b, acc[t], 0, 0, 0);
            acc[t] = __builtin_amdgcn_mfma_f32_16x16x32_bf16(al, bh.b, acc[t], 0, 0, 0);
        }
    }

    // ---- epilogue: D rows 0..7 (quad 0,1) + bias -> LDS qkv tile ----
    __syncthreads();   // all A reads done before union overwrite
    #pragma unroll
    for (int t = 0; t < 3; ++t) {
        const int chb = chw + t * 16;
        const float* __restrict__ bp = (chb < 256) ? bq : (chb < 512) ? bk : bv;
        const float bias = bp[(chb & 255) + ln];
        if (quad < 2) {
            #pragma unroll
            for (int reg = 0; reg < 4; ++reg) {
                const int tok = quad * 4 + reg;     // 0..7
                sm.qkv[tok * QSTR + chb + ln] = acc[t][reg] + bias;
            }
        }
    }
    __syncthreads();

    // ---- Phase 2: Taylor attention; 2 waves per token (i-halves) ----
    {
        const int tok  = wid >> 1;
        const int half = wid & 1;
        const int l    = lane;
        const float* __restrict__ base = &sm.qkv[tok * QSTR];

        const float4 k4 = *(const float4*)(base + FD + 4 * l);
        const float4 v4 = *(const float4*)(base + 2 * FD + 4 * l);
        const float ke[4] = {k4.x, k4.y, k4.z, k4.w};
        const float ve[4] = {v4.x, v4.y, v4.z, v4.w};

        float G[NM], Mo[NM];
        #pragma unroll
        for (int n = 0; n < NM; ++n) { G[n] = 0.f; Mo[n] = 0.f; }
        #pragma unroll
        for (int e = 0; e < 4; ++e) {
            float kp = 1.f;
            #pragma unroll
            for (int n = 0; n < NM; ++n) {
                G[n] += kp;
                Mo[n] = fmaf(kp, ve[e], Mo[n]);
                kp *= ke[e];
            }
        }
        #pragma unroll
        for (int n = 0; n < NM; ++n) {
            #pragma unroll
            for (int off = 1; off < 64; off <<= 1) {
                G[n]  += __shfl_xor(G[n],  off);
                Mo[n] += __shfl_xor(Mo[n], off);
            }
        }

        constexpr float inv_fact[NM] = {
            1.f, 1.f, 0.5f, 1.f/6.f, 1.f/24.f, 1.f/120.f, 1.f/720.f,
            1.f/5040.f, 1.f/40320.f, 1.f/362880.f, 1.f/3628800.f,
            1.f/39916800.f, 1.f/479001600.f, 1.f/6227020800.f,
            1.f/87178291200.f};
        float am[NM], ag[NM];
        #pragma unroll
        for (int n = 0; n < NM; ++n) {
            am[n] = Mo[n] * inv_fact[n];
            ag[n] = G[n]  * inv_fact[n];
        }

        const int ib = half * 128 + 2 * l;          // 2 channels per lane
        const float2 q2 = *(const float2*)(base + ib);
        const float qe[2] = {q2.x, q2.y};
        float re[2];
        #pragma unroll
        for (int e = 0; e < 2; ++e) {
            const float cc = qe[e] * 0.0625f;       // c = Q_i / sqrt(256)
            float Pm = am[NM - 1], Pg = ag[NM - 1];
            #pragma unroll
            for (int n = NM - 2; n >= 0; --n) {
                Pm = fmaf(Pm, cc, am[n]);
                Pg = fmaf(Pg, cc, ag[n]);
            }
            re[e] = Pm * fast_rcp(Pg);
        }
        float2 res; res.x = re[0]; res.y = re[1];
        *(float2*)(out + (size_t)(t0 + tok) * FD + ib) = res;
    }
}

extern "C" void kernel_launch(void* const* d_in, const int* in_sizes, int n_in,
                              void* d_out, int out_size, void* d_ws, size_t ws_size,
                              hipStream_t stream) {
    const float* x  = (const float*)d_in[0];
    const float* Wq = (const float*)d_in[1];
    const float* bq = (const float*)d_in[2];
    const float* Wk = (const float*)d_in[3];
    const float* bk = (const float*)d_in[4];
    const float* Wv = (const float*)d_in[5];
    const float* bv = (const float*)d_in[6];
    float* out = (float*)d_out;

    const int M = in_sizes[0] / FD;   // 2048 tokens

    fused_ja<<<M / TB, NT, 0, stream>>>(x, Wq, bq, Wk, bk, Wv, bv, out);
}